// Round 8
// baseline (391.816 us; speedup 1.0000x reference)
//
#include <hip/hip_runtime.h>
#include <stdint.h>

// ---------------------------------------------------------------------------
// GC_FFM fusion block on MI355X (gfx950), bf16 MFMA pipeline.
// N=2, C=256, RC=32, H=W=64, HW=4096.
// R8: attn v4 — producer/consumer wave specialization. 512-thr blocks,
//     waves 0-3 produce exp(S) tiles (double-buffered PT), waves 4-7 do
//     pure PV MFMA with register-prefetched V frags. 1 barrier/iter,
//     exp redundancy halved (256c per block).
// R5 lesson: LDS-free GEMMs with large-stride operands = latency-bound.
// R6 lesson: LDS transpose scatter (scalar b16) = conflict+VALU wall.
// ---------------------------------------------------------------------------

typedef __bf16 bf16_t;
typedef __bf16 bf16x8 __attribute__((ext_vector_type(8)));
typedef float f32x4 __attribute__((ext_vector_type(4)));

#define HW 4096
#define NB 2

__device__ inline f32x4 mfma_bf16(bf16x8 a, bf16x8 b, f32x4 c) {
    return __builtin_amdgcn_mfma_f32_16x16x32_bf16(a, b, c, 0, 0, 0);
}

// ---------------------------------------------------------------------------
// Batched fp32 -> bf16 conversion (one launch for all weights + features).
// ---------------------------------------------------------------------------
#define MAXJOB 12
struct CvtJobs {
    const float* src[MAXJOB];
    bf16_t* dst[MAXJOB];
    int vend[MAXJOB];     // cumulative end, vec8 units
    int rowlen[MAXJOB];
    int rowstride[MAXJOB];
    int rowoff[MAXJOB];
};

__global__ __launch_bounds__(256) void convert_batch_k(CvtJobs J, int totalvec) {
    int gv = blockIdx.x * 256 + threadIdx.x;
    if (gv >= totalvec) return;
    int j = 0;
    while (gv >= J.vend[j]) j++;
    int vbase = (j == 0) ? 0 : J.vend[j - 1];
    int e = (gv - vbase) * 8;
    const float* s = J.src[j] + e;
    float4 f0 = *(const float4*)s;
    float4 f1 = *(const float4*)(s + 4);
    bf16x8 o;
    o[0] = (bf16_t)f0.x; o[1] = (bf16_t)f0.y; o[2] = (bf16_t)f0.z; o[3] = (bf16_t)f0.w;
    o[4] = (bf16_t)f1.x; o[5] = (bf16_t)f1.y; o[6] = (bf16_t)f1.z; o[7] = (bf16_t)f1.w;
    int di = e;
    if (J.rowlen[j])
        di = (e / J.rowlen[j]) * J.rowstride[j] + J.rowoff[j] + (e % J.rowlen[j]);
    *(bf16x8*)(J.dst[j] + di) = o;
}

// pack q/k biases into stacked [64] buffers + combined skip/fus3 bias
__global__ __launch_bounds__(256) void pack_bias_k(const float* qr, const float* kr,
                                                   const float* qd, const float* kd,
                                                   const float* sb, const float* fb,
                                                   float* BQK_R, float* BQK_D, float* BSUM) {
    int t = threadIdx.x;
    if (t < 32) {
        BQK_R[t] = qr[t]; BQK_R[32 + t] = kr[t];
        BQK_D[t] = qd[t]; BQK_D[32 + t] = kd[t];
    }
    BSUM[t] = sb[t] + fb[t];
}

// fus2_w [O=512][C=512][3][3] -> A'[o][ (dy*3+dx)*512 + c ]
__global__ __launch_bounds__(256) void reorder_fus2_k(const float* __restrict__ src,
                                                      bf16_t* __restrict__ dst) {
    int idx = blockIdx.x * 256 + threadIdx.x;
    if (idx >= 512 * 4608) return;
    int o = idx / 4608;
    int t = idx % 4608;
    int t9 = t / 512;
    int c  = t % 512;
    dst[idx] = (bf16_t)src[(size_t)o * 4608 + c * 9 + t9];
}

// ---------------------------------------------------------------------------
// Generic bf16 GEMM (R4-proven): out = epi( A[z] . B[z] + bias ), dual-A.
// EPI: 0 none->fp32, 1 relu->bf16, 3 col-div by aux, 5 gate-fuse,
//      6 QKT transposed store, 7 NHWC transposed relu store (Y1)
// ---------------------------------------------------------------------------
template <int EPI, bool OUT_BF16>
__global__ __launch_bounds__(256) void gemm_k(const bf16_t* __restrict__ A,
                                              const bf16_t* __restrict__ A2,
                                              const bf16_t* __restrict__ B,
                                              const float* __restrict__ bias,
                                              const float* __restrict__ bias2,
                                              void* __restrict__ outp,
                                              const void* __restrict__ aux,
                                              int M, int K, size_t strideB, size_t strideO) {
    __shared__ bf16_t Bt[64][72];
    const int t = threadIdx.x;
    const int mb = blockIdx.x, jb = blockIdx.y, n = blockIdx.z;
    const int w = t >> 6, lane = t & 63, quad = lane >> 4, l16 = lane & 15;

    const bf16_t* Au = (n >= 2) ? A2 : A;
    const float* biasu = (n >= 2) ? bias2 : bias;

    const bf16_t* Bb = B + (size_t)n * strideB + jb * 64;
    const int srow = t >> 2;
    const int scol = (t & 3) << 4;

    f32x4 zero = {0.f, 0.f, 0.f, 0.f};
    f32x4 acc[4] = {zero, zero, zero, zero};

    const bf16_t* Arow = Au + (size_t)(mb * 64 + w * 16 + l16) * K + quad * 8;

    for (int k0 = 0; k0 < K; k0 += 64) {
        const bf16_t* src = Bb + (size_t)(k0 + srow) * HW + scol;
        bf16x8 v0 = *(const bf16x8*)src;
        bf16x8 v1 = *(const bf16x8*)(src + 8);
        __syncthreads();
#pragma unroll
        for (int e = 0; e < 8; e++) Bt[scol + e][srow] = v0[e];
#pragma unroll
        for (int e = 0; e < 8; e++) Bt[scol + 8 + e][srow] = v1[e];
        __syncthreads();

        bf16x8 a0 = *(const bf16x8*)(Arow + k0);
        bf16x8 a1 = *(const bf16x8*)(Arow + k0 + 32);
#pragma unroll
        for (int ns = 0; ns < 4; ns++) {
            bf16x8 b0 = *(const bf16x8*)&Bt[ns * 16 + l16][quad * 8];
            bf16x8 b1 = *(const bf16x8*)&Bt[ns * 16 + l16][32 + quad * 8];
            acc[ns] = mfma_bf16(a0, b0, acc[ns]);
            acc[ns] = mfma_bf16(a1, b1, acc[ns]);
        }
    }

    if (EPI == 6) {
        // transposed store: QKT[z][col][64] (M=64, mb=0)
#pragma unroll
        for (int ns = 0; ns < 4; ns++) {
            int col = jb * 64 + ns * 16 + l16;
            union { bf16_t h[4]; unsigned long long u; } pk;
#pragma unroll
            for (int rr = 0; rr < 4; rr++) {
                int m = w * 16 + quad * 4 + rr;
                pk.h[rr] = (bf16_t)(acc[ns][rr] + biasu[m]);
            }
            *(unsigned long long*)((bf16_t*)outp +
                ((size_t)n * HW + col) * 64 + w * 16 + quad * 4) = pk.u;
        }
    } else if (EPI == 7) {
        // NHWC transposed relu store: Y1[(n*HW + col)*512 + m_base..+4]
        const int m_base = mb * 64 + w * 16 + quad * 4;
#pragma unroll
        for (int ns = 0; ns < 4; ns++) {
            int col = jb * 64 + ns * 16 + l16;
            union { bf16_t h[4]; unsigned long long u; } pk;
#pragma unroll
            for (int rr = 0; rr < 4; rr++) {
                float v = acc[ns][rr] + biasu[m_base + rr];
                pk.h[rr] = (bf16_t)(v > 0.f ? v : 0.f);
            }
            *(unsigned long long*)((bf16_t*)outp +
                ((size_t)n * HW + col) * 512 + m_base) = pk.u;
        }
    } else if (EPI == 5) {
        const bf16_t* catp = (const bf16_t*)aux;
        bf16_t* f = (bf16_t*)outp;
#pragma unroll
        for (int ns = 0; ns < 4; ns++) {
#pragma unroll
            for (int rr = 0; rr < 4; rr++) {
                int m = mb * 64 + w * 16 + quad * 4 + rr;
                int col = jb * 64 + ns * 16 + l16;
                float v = acc[ns][rr] + biasu[m];
                float g = 1.f / (1.f + __expf(-v));
                size_t base = (size_t)n * 512 * HW + (size_t)m * HW + col;
                float br = (float)catp[base];
                float bd = (float)catp[base + (size_t)256 * HW];
                size_t ob = (size_t)n * 1024 * HW + (size_t)m * HW + col;
                f[ob] = (bf16_t)(br * g + bd * (1.f - g));
                f[ob + (size_t)256 * HW] = (bf16_t)(br * bd);
            }
        }
    } else {
#pragma unroll
        for (int ns = 0; ns < 4; ns++) {
#pragma unroll
            for (int rr = 0; rr < 4; rr++) {
                int m = mb * 64 + w * 16 + quad * 4 + rr;
                int col = jb * 64 + ns * 16 + l16;
                float v = acc[ns][rr] + biasu[m];
                if (EPI == 1) v = v > 0.f ? v : 0.f;
                else if (EPI == 3) v = v / ((const float*)aux)[n * HW + col];
                size_t oi = (size_t)n * strideO + (size_t)m * HW + col;
                if (OUT_BF16) ((bf16_t*)outp)[oi] = (bf16_t)v;
                else ((float*)outp)[oi] = v;
            }
        }
    }
}

// ---------------------------------------------------------------------------
// conv3x3 implicit GEMM v2 (R7-proven): NHWC input, vectorized transpose-free
// LDS staging, 128 m x 64 px per block, NCHW output.
// ---------------------------------------------------------------------------
__global__ __launch_bounds__(256) void conv3_k(const bf16_t* __restrict__ A,
                                               const bf16_t* __restrict__ Y1n,
                                               const float* __restrict__ bias,
                                               bf16_t* __restrict__ outp,
                                               size_t strideN) {
    __shared__ bf16_t kTn[198][72];  // [px_slot][channel], pad 72 (144B rows)
    const int t = threadIdx.x;
    const int mb = blockIdx.x, y = blockIdx.y, n = blockIdx.z;
    const int w = t >> 6, lane = t & 63, quad = lane >> 4, l16 = lane & 15;

    f32x4 zero = {0.f, 0.f, 0.f, 0.f};
    f32x4 acc[2][4];
#pragma unroll
    for (int i = 0; i < 2; i++)
#pragma unroll
        for (int j = 0; j < 4; j++) acc[i][j] = zero;

    const bf16_t* Yb = Y1n + (size_t)n * HW * 512;

    const bf16_t* Arow0 = A + (size_t)(mb * 128 + w * 32 + l16) * 4608 + quad * 8;
    const bf16_t* Arow1 = Arow0 + (size_t)16 * 4608;

    int pxs[7], seg[7], gidx[7];
    bool ok[7], act[7];
#pragma unroll
    for (int i = 0; i < 7; i++) {
        int slot = t + i * 256;
        act[i] = slot < 1584;
        int ps = act[i] ? (slot >> 3) : 0;
        pxs[i] = ps;
        seg[i] = slot & 7;
        int r = ps / 66, xm = ps % 66;
        int yy = y + r - 1, xx = xm - 1;
        ok[i] = act[i] && ((unsigned)yy < 64u) && ((unsigned)xx < 64u);
        gidx[i] = ok[i] ? (yy * 64 + xx) : 0;
    }

    for (int c0 = 0; c0 < 512; c0 += 64) {
        bf16x8 vals[7];
#pragma unroll
        for (int i = 0; i < 7; i++) {
            bf16x8 v;
            if (ok[i]) {
                v = *(const bf16x8*)(Yb + (size_t)gidx[i] * 512 + c0 + seg[i] * 8);
            } else {
#pragma unroll
                for (int e = 0; e < 8; e++) v[e] = (bf16_t)0.f;
            }
            vals[i] = v;
        }
        __syncthreads();
#pragma unroll
        for (int i = 0; i < 7; i++)
            if (act[i]) *(bf16x8*)&kTn[pxs[i]][seg[i] * 8] = vals[i];
        __syncthreads();

#pragma unroll
        for (int t9 = 0; t9 < 9; t9++) {
            const int dy = t9 / 3, dx = t9 % 3;
            const bf16_t* ap0 = Arow0 + t9 * 512 + c0;
            const bf16_t* ap1 = Arow1 + t9 * 512 + c0;
            bf16x8 a00 = *(const bf16x8*)(ap0);
            bf16x8 a01 = *(const bf16x8*)(ap0 + 32);
            bf16x8 a10 = *(const bf16x8*)(ap1);
            bf16x8 a11 = *(const bf16x8*)(ap1 + 32);
#pragma unroll
            for (int ns = 0; ns < 4; ns++) {
                int p = dy * 66 + ns * 16 + l16 + dx;
                bf16x8 b0 = *(const bf16x8*)&kTn[p][quad * 8];
                bf16x8 b1 = *(const bf16x8*)&kTn[p][32 + quad * 8];
                acc[0][ns] = mfma_bf16(a00, b0, acc[0][ns]);
                acc[0][ns] = mfma_bf16(a01, b1, acc[0][ns]);
                acc[1][ns] = mfma_bf16(a10, b0, acc[1][ns]);
                acc[1][ns] = mfma_bf16(a11, b1, acc[1][ns]);
            }
        }
    }

#pragma unroll
    for (int ms = 0; ms < 2; ms++) {
#pragma unroll
        for (int ns = 0; ns < 4; ns++) {
#pragma unroll
            for (int rr = 0; rr < 4; rr++) {
                int m = mb * 128 + w * 32 + ms * 16 + quad * 4 + rr;
                int x = ns * 16 + l16;
                float v = acc[ms][ns][rr] + bias[m];
                v = v > 0.f ? v : 0.f;
                outp[(size_t)n * strideN + (size_t)m * HW + y * 64 + x] = (bf16_t)v;
            }
        }
    }
}

// ---------------------------------------------------------------------------
// Attention pass A v2 (R6-proven): Z[k][i] = sum_j exp(S[i,j]).
// ---------------------------------------------------------------------------
__global__ __launch_bounds__(256) void rowsum_k(const bf16_t* __restrict__ QKT,
                                                float* __restrict__ Z) {
    __shared__ float Zp[2][32];
    const int t = threadIdx.x, ib = blockIdx.x, k = blockIdx.y;
    const int w = t >> 6, lane = t & 63, quad = lane >> 4, l16 = lane & 15;
    const int is = w & 1, jh = w >> 1;
    const int qs = k ^ 2;
    const bf16_t* Q = QKT + (size_t)qs * HW * 64;

    bf16x8 a = *(const bf16x8*)(Q + (size_t)(ib * 32 + is * 16 + l16) * 64 + quad * 8);
    float zacc[4] = {0.f, 0.f, 0.f, 0.f};
    f32x4 zero = {0.f, 0.f, 0.f, 0.f};

    for (int jt = jh * 32; jt < jh * 32 + 32; jt++) {
#pragma unroll
        for (int ns = 0; ns < 4; ns++) {
            bf16x8 b = *(const bf16x8*)(Q + (size_t)(jt * 64 + ns * 16 + l16) * 64 + 32 + quad * 8);
            f32x4 s = mfma_bf16(a, b, zero);
#pragma unroll
            for (int rr = 0; rr < 4; rr++) zacc[rr] += __expf(s[rr]);
        }
    }

#pragma unroll
    for (int rr = 0; rr < 4; rr++) {
        for (int mask = 1; mask < 16; mask <<= 1)
            zacc[rr] += __shfl_xor(zacc[rr], mask, 64);
    }
    if (l16 == 0) {
#pragma unroll
        for (int rr = 0; rr < 4; rr++)
            Zp[jh][is * 16 + quad * 4 + rr] = zacc[rr];
    }
    __syncthreads();
    if (t < 32)
        Z[(size_t)k * HW + ib * 32 + t] = Zp[0][t] + Zp[1][t];
}

// ---------------------------------------------------------------------------
// Attention pass B v4: producer/consumer wave specialization.
// Block = 512 threads (8 waves) covering 256 c x 64 j, grid (64 jb, 4 z).
// Waves 0-3 (producers): S tile for iter it+1 -> exp -> PT[(it+1)&1].
// Waves 4-7 (consumers): PV MFMA from PT[it&1], V frags prefetched to regs.
// One barrier per iteration; exp latency decoupled from MFMA issue.
// ---------------------------------------------------------------------------
__global__ __launch_bounds__(512) void attn4_k(const bf16_t* __restrict__ QKT,
                                               const bf16_t* __restrict__ V,
                                               const float* __restrict__ rgb_feat,
                                               const float* __restrict__ chm_feat,
                                               bf16_t* __restrict__ CAT) {
    __shared__ bf16_t PT[2][64][72];  // [buf][j_local][i_local]
    const int t = threadIdx.x, jb = blockIdx.x, z = blockIdx.y;
    const int w = t >> 6, lane = t & 63, quad = lane >> 4, l16 = lane & 15;
    const int qs = z ^ 2, n = z & 1;
    const bool prod = (w < 4);
    const int pw = w, cw = w - 4;

    const bf16_t* Q = QKT + (size_t)qs * HW * 64;
    f32x4 zero = {0.f, 0.f, 0.f, 0.f};

    // ---- producer state ----
    bf16x8 bS[4];
    if (prod) {
#pragma unroll
        for (int ns = 0; ns < 4; ns++)
            bS[ns] = *(const bf16x8*)(Q + (size_t)(jb * 64 + ns * 16 + l16) * 64 + 32 + quad * 8);
    }
    // ---- consumer state ----
    f32x4 acc[4][4];
#pragma unroll
    for (int i = 0; i < 4; i++)
#pragma unroll
        for (int j = 0; j < 4; j++) acc[i][j] = zero;
    const bf16_t* Vp = V + ((size_t)z * 256 + cw * 16 + l16) * HW + quad * 8;  // + ct*64*HW
    bf16x8 aV[4][2], aVn[4][2];

    // ---- prologue: produce PT[0] / load aV(it=0) ----
    if (prod) {
        bf16x8 aS = *(const bf16x8*)(Q + (size_t)(pw * 16 + l16) * 64 + quad * 8);
#pragma unroll
        for (int ns = 0; ns < 4; ns++) {
            f32x4 s = mfma_bf16(aS, bS[ns], zero);
            union { bf16_t h[4]; unsigned long long u; } pk;
#pragma unroll
            for (int rr = 0; rr < 4; rr++) pk.h[rr] = (bf16_t)__expf(s[rr]);
            *(unsigned long long*)&PT[0][ns * 16 + l16][pw * 16 + quad * 4] = pk.u;
        }
    } else {
#pragma unroll
        for (int ct = 0; ct < 4; ct++) {
            aV[ct][0] = *(const bf16x8*)(Vp + (size_t)ct * 64 * HW);
            aV[ct][1] = *(const bf16x8*)(Vp + (size_t)ct * 64 * HW + 32);
        }
    }
    __syncthreads();

    for (int it = 0; it < 64; it++) {
        const int p = it & 1;
        if (prod) {
            if (it < 63) {
                bf16x8 aS = *(const bf16x8*)(Q + (size_t)((it + 1) * 64 + pw * 16 + l16) * 64 + quad * 8);
#pragma unroll
                for (int ns = 0; ns < 4; ns++) {
                    f32x4 s = mfma_bf16(aS, bS[ns], zero);
                    union { bf16_t h[4]; unsigned long long u; } pk;
#pragma unroll
                    for (int rr = 0; rr < 4; rr++) pk.h[rr] = (bf16_t)__expf(s[rr]);
                    *(unsigned long long*)&PT[p ^ 1][ns * 16 + l16][pw * 16 + quad * 4] = pk.u;
                }
            }
        } else {
            if (it < 63) {
                const bf16_t* vp = Vp + (it + 1) * 64;
#pragma unroll
                for (int ct = 0; ct < 4; ct++) {
                    aVn[ct][0] = *(const bf16x8*)(vp + (size_t)ct * 64 * HW);
                    aVn[ct][1] = *(const bf16x8*)(vp + (size_t)ct * 64 * HW + 32);
                }
            }
#pragma unroll
            for (int ns = 0; ns < 4; ns++) {
                bf16x8 b0 = *(const bf16x8*)&PT[p][ns * 16 + l16][quad * 8];
                bf16x8 b1 = *(const bf16x8*)&PT[p][ns * 16 + l16][32 + quad * 8];
#pragma unroll
                for (int ct = 0; ct < 4; ct++) {
                    acc[ct][ns] = mfma_bf16(aV[ct][0], b0, acc[ct][ns]);
                    acc[ct][ns] = mfma_bf16(aV[ct][1], b1, acc[ct][ns]);
                }
            }
        }
        __syncthreads();
        if (!prod && it < 63) {
#pragma unroll
            for (int ct = 0; ct < 4; ct++) {
                aV[ct][0] = aVn[ct][0];
                aV[ct][1] = aVn[ct][1];
            }
        }
    }

    if (!prod) {
        const float* feat = ((z < 2) ? rgb_feat : chm_feat) + (size_t)n * 256 * HW;
        bf16_t* outp = CAT + (size_t)n * 512 * HW + (size_t)(z < 2 ? 0 : 256) * HW;
#pragma unroll
        for (int ct = 0; ct < 4; ct++) {
#pragma unroll
            for (int ns = 0; ns < 4; ns++) {
#pragma unroll
                for (int rr = 0; rr < 4; rr++) {
                    int c = ct * 64 + cw * 16 + quad * 4 + rr;
                    int col = jb * 64 + ns * 16 + l16;
                    float v = acc[ct][ns][rr] + feat[(size_t)c * HW + col];
                    outp[(size_t)c * HW + col] = (bf16_t)v;
                }
            }
        }
    }
}

// ---------------------------------------------------------------------------
extern "C" void kernel_launch(void* const* d_in, const int* in_sizes, int n_in,
                              void* d_out, int out_size, void* d_ws, size_t ws_size,
                              hipStream_t stream) {
    (void)in_sizes; (void)n_in; (void)out_size; (void)ws_size;

    const float* rgb_feat  = (const float*)d_in[0];
    const float* chm_feat  = (const float*)d_in[1];
    const float* rgb_q_w   = (const float*)d_in[2];
    const float* rgb_q_b   = (const float*)d_in[3];
    const float* rgb_k_w   = (const float*)d_in[4];
    const float* rgb_k_b   = (const float*)d_in[5];
    const float* rgb_v_w   = (const float*)d_in[6];
    const float* rgb_v_b   = (const float*)d_in[7];
    const float* depth_q_w = (const float*)d_in[8];
    const float* depth_q_b = (const float*)d_in[9];
    const float* depth_k_w = (const float*)d_in[10];
    const float* depth_k_b = (const float*)d_in[11];
    const float* depth_v_w = (const float*)d_in[12];
    const float* depth_v_b = (const float*)d_in[13];
    const float* gate_w    = (const float*)d_in[14];
    const float* gate_b    = (const float*)d_in[15];
    const float* fus1_w    = (const float*)d_in[16];
    const float* fus1_b    = (const float*)d_in[17];
    const float* fus2_w    = (const float*)d_in[18];
    const float* fus2_b    = (const float*)d_in[19];
    const float* fus3_w    = (const float*)d_in[20];
    const float* fus3_b    = (const float*)d_in[21];
    const float* skip_w    = (const float*)d_in[22];
    const float* skip_b    = (const float*)d_in[23];

    char* ws = (char*)d_ws;
    size_t off = 0;
    auto alloc = [&](size_t bytes) -> char* {
        char* p = ws + off;
        off += (bytes + 255) & ~(size_t)255;
        return p;
    };

    bf16_t* WQK_R = (bf16_t*)alloc(64 * 256 * 2);
    bf16_t* WQK_D = (bf16_t*)alloc(64 * 256 * 2);
    bf16_t* WV_R  = (bf16_t*)alloc(256 * 256 * 2);
    bf16_t* WV_D  = (bf16_t*)alloc(256 * 256 * 2);
    bf16_t* WGATE = (bf16_t*)alloc(256 * 512 * 2);
    bf16_t* WFUS1 = (bf16_t*)alloc(512 * 512 * 2);
    bf16_t* WFUS2 = (bf16_t*)alloc(512 * 4608 * 2);
    bf16_t* WCAT  = (bf16_t*)alloc(256 * 1024 * 2);      // [skip_w | fus3_w]
    float*  BQK_R = (float*)alloc(64 * 4);
    float*  BQK_D = (float*)alloc(64 * 4);
    float*  BSUM  = (float*)alloc(256 * 4);
    bf16_t* XB    = (bf16_t*)alloc((size_t)4 * 256 * HW * 2);    // [XR n0,n1; XC n0,n1]
    bf16_t* QKT   = (bf16_t*)alloc((size_t)4 * HW * 64 * 2);     // [z][pixel][64]
    float*  ZBUF  = (float*)alloc((size_t)4 * HW * 4);           // [k][HW]
    bf16_t* V4    = (bf16_t*)alloc((size_t)4 * 256 * HW * 2);    // CHW [z][c][pixel]
    bf16_t* CAT   = (bf16_t*)alloc((size_t)NB * 512 * HW * 2);
    bf16_t* FY    = (bf16_t*)alloc((size_t)NB * 1024 * HW * 2);  // [F ; Y2] NCHW
    bf16_t* Y1    = (bf16_t*)alloc((size_t)NB * HW * 512 * 2);   // NHWC [n][pix][512]

    bf16_t* XR = XB;
    bf16_t* XC = XB + (size_t)2 * 256 * HW;

    // ---- prep: batched convert + bias pack ---------------------------------
    CvtJobs J;
    int cum = 0, nj = 0;
    auto addjob = [&](const float* s, bf16_t* d, int cnt, int rl, int rs, int ro) {
        J.src[nj] = s; J.dst[nj] = d; cum += cnt / 8; J.vend[nj] = cum;
        J.rowlen[nj] = rl; J.rowstride[nj] = rs; J.rowoff[nj] = ro; nj++;
    };
    addjob(rgb_feat, XR, NB * 256 * HW, 0, 0, 0);
    addjob(chm_feat, XC, NB * 256 * HW, 0, 0, 0);
    addjob(rgb_q_w, WQK_R, 32 * 256, 0, 0, 0);
    addjob(rgb_k_w, WQK_R + 32 * 256, 32 * 256, 0, 0, 0);
    addjob(depth_q_w, WQK_D, 32 * 256, 0, 0, 0);
    addjob(depth_k_w, WQK_D + 32 * 256, 32 * 256, 0, 0, 0);
    addjob(rgb_v_w, WV_R, 256 * 256, 0, 0, 0);
    addjob(depth_v_w, WV_D, 256 * 256, 0, 0, 0);
    addjob(gate_w, WGATE, 256 * 512, 0, 0, 0);
    addjob(fus1_w, WFUS1, 512 * 512, 0, 0, 0);
    addjob(skip_w, WCAT, 256 * 512, 512, 1024, 0);
    addjob(fus3_w, WCAT, 256 * 512, 512, 1024, 512);
    int totalvec = cum;
    convert_batch_k<<<dim3((totalvec + 255) / 256), 256, 0, stream>>>(J, totalvec);
    reorder_fus2_k<<<dim3(512 * 4608 / 256), 256, 0, stream>>>(fus2_w, WFUS2);
    pack_bias_k<<<dim3(1), 256, 0, stream>>>(rgb_q_b, rgb_k_b, depth_q_b, depth_k_b,
                                             skip_b, fus3_b, BQK_R, BQK_D, BSUM);

    // ---- q/k projections -> QKT[z][pixel][64] (z: 0,1 rgb; 2,3 depth) ------
    gemm_k<6, true><<<dim3(1, 64, 4), 256, 0, stream>>>(
        WQK_R, WQK_D, XB, BQK_R, BQK_D, QKT, nullptr, 64, 256, (size_t)256 * HW, 0);

    // ---- attention pass A: softmax denominators ----------------------------
    rowsum_k<<<dim3(128, 4), 256, 0, stream>>>(QKT, ZBUF);

    // ---- v projections, folded 1/Z scale -> V4 CHW -------------------------
    gemm_k<3, true><<<dim3(4, 64, 4), 256, 0, stream>>>(
        WV_R, WV_D, XB, rgb_v_b, depth_v_b, V4, ZBUF, 256, 256, (size_t)256 * HW, (size_t)256 * HW);

    // ---- attention pass B + residual -> CAT=[br;bd] NCHW -------------------
    attn4_k<<<dim3(64, 4), 512, 0, stream>>>(QKT, V4, rgb_feat, chm_feat, CAT);

    // ---- gate + gated fusion fused epilogue -> FY rows 0..511 --------------
    gemm_k<5, true><<<dim3(4, 64, NB), 256, 0, stream>>>(
        WGATE, WGATE, CAT, gate_b, gate_b, FY, CAT, 256, 512, (size_t)512 * HW, 0);

    // ---- fus1 (relu) -> Y1 NHWC --------------------------------------------
    gemm_k<7, true><<<dim3(8, 64, NB), 256, 0, stream>>>(
        WFUS1, WFUS1, FY, fus1_b, fus1_b, Y1, nullptr, 512, 512, (size_t)1024 * HW, 0);

    // ---- fus2 conv3x3 (relu) -> FY rows 512..1023 --------------------------
    conv3_k<<<dim3(4, 64, NB), 256, 0, stream>>>(WFUS2, Y1, fus2_b,
                                                 FY + (size_t)512 * HW, (size_t)1024 * HW);

    // ---- merged skip+fus3: d_out = [skip_w|fus3_w] . [F;Y2] + (skip_b+fus3_b)
    gemm_k<0, false><<<dim3(4, 64, NB), 256, 0, stream>>>(
        WCAT, WCAT, FY, BSUM, BSUM, d_out, nullptr, 256, 1024, (size_t)1024 * HW, (size_t)256 * HW);
}